// Round 9
// baseline (172.380 us; speedup 1.0000x reference)
//
#include <hip/hip_runtime.h>

#define N_   32
#define C_   3
#define T_   300
#define V_   25
#define OUT_ 96
#define ROWP 28              // padded row (float4-aligned)
#define ATS  (V_*ROWP)       // 700 floats per t-slice
#define TTP  5               // t's per k_powsum block
#define NCH  (T_/TTP)        // 60 chunks per n
#define TT2  10              // t's per k_out block
#define SEL  (3*V_*V_)       // 1875 floats per sum record

// ---------------------------------------------------------------------------
// K1: round-5 version, byte-identical. block = (n, 5-t chunk), 128 threads.
// ---------------------------------------------------------------------------
__global__ __launch_bounds__(128) void k_powsum(const float* __restrict__ xx,
                                                float* __restrict__ partial) {
    const int n = blockIdx.x, chunk = blockIdx.y;
    const int tid = threadIdx.x;

    __shared__ __align__(16) float xs[C_*TTP*ROWP];  // 420
    __shared__ __align__(16) float A [TTP*ATS];      // 3500
    __shared__ __align__(16) float A2[TTP*ATS];      // 3500

    const float* xxn = xx + (size_t)n * C_*T_*V_;
    const int t0 = chunk * TTP;

    for (int i = tid; i < C_*TTP*ROWP; i += 128) {
        const int c = i/(TTP*ROWP), r = i%(TTP*ROWP), t = r/ROWP, u = r%ROWP;
        xs[i] = (u < V_) ? xxn[c*(T_*V_) + (t0+t)*V_ + u] : ((c==0)?1e18f:0.f);
    }
    if (tid < TTP*V_) {
        float* p = &A2[(tid/V_)*ATS + (tid%V_)*ROWP];
        p[25]=0.f; p[26]=0.f; p[27]=0.f;
    }
    __syncthreads();

    if (tid < TTP*V_) {
        const int slot = tid/V_, v = tid%V_;
        const float* x0 = &xs[0*(TTP*ROWP) + slot*ROWP];
        const float* x1 = &xs[1*(TTP*ROWP) + slot*ROWP];
        const float* x2 = &xs[2*(TTP*ROWP) + slot*ROWP];
        const float xv0 = x0[v], xv1 = x1[v], xv2 = x2[v];
        float* Arow = &A[slot*ATS + v*ROWP];
        #pragma unroll
        for (int u4 = 0; u4 < ROWP; u4 += 4) {
            const float4 q0 = *(const float4*)&x0[u4];
            const float4 q1 = *(const float4*)&x1[u4];
            const float4 q2 = *(const float4*)&x2[u4];
            float4 a;
            {   float d0=xv0-q0.x, d1=xv1-q1.x, d2=xv2-q2.x;
                a.x = __expf(-(d0*d0 + d1*d1 + d2*d2)); }
            {   float d0=xv0-q0.y, d1=xv1-q1.y, d2=xv2-q2.y;
                a.y = __expf(-(d0*d0 + d1*d1 + d2*d2)); }
            {   float d0=xv0-q0.z, d1=xv1-q1.z, d2=xv2-q2.z;
                a.z = __expf(-(d0*d0 + d1*d1 + d2*d2)); }
            {   float d0=xv0-q0.w, d1=xv1-q1.w, d2=xv2-q2.w;
                a.w = __expf(-(d0*d0 + d1*d1 + d2*d2)); }
            *(float4*)&Arow[u4] = a;
        }
    }
    __syncthreads();

    const bool act = (tid < TTP*15);
    const int slot = tid / 15;
    int ti = 0, tj = 0;
    {
        int r = tid % 15;
        #pragma unroll
        for (int i = 0; i < 5; ++i) {
            const int cnt = 5 - i;
            if (r < cnt) { ti = i; tj = i + r; break; }
            r -= cnt;
        }
    }
    const int vt = ti*5, ut = tj*5;

    if (act) {
        float acc[5][5];
        #pragma unroll
        for (int a=0;a<5;a++)
            #pragma unroll
            for (int b2=0;b2<5;b2++) acc[a][b2]=0.f;
        const float* Ab = &A[slot*ATS];
        #pragma unroll
        for (int w = 0; w < ROWP; w += 4) {
            float4 ar[5], au[5];
            #pragma unroll
            for (int a=0;a<5;a++) ar[a] = *(const float4*)&Ab[(vt+a)*ROWP + w];
            #pragma unroll
            for (int b2=0;b2<5;b2++) au[b2] = *(const float4*)&Ab[(ut+b2)*ROWP + w];
            #pragma unroll
            for (int a=0;a<5;a++)
                #pragma unroll
                for (int b2=0;b2<5;b2++)
                    acc[a][b2] += ar[a].x*au[b2].x + ar[a].y*au[b2].y
                                + ar[a].z*au[b2].z + ar[a].w*au[b2].w;
        }
        float* A2b = &A2[slot*ATS];
        #pragma unroll
        for (int a=0;a<5;a++)
            #pragma unroll
            for (int b2=0;b2<5;b2++) {
                A2b[(vt+a)*ROWP + ut+b2] = acc[a][b2];
                A2b[(ut+b2)*ROWP + vt+a] = acc[a][b2];
            }
    }
    __syncthreads();

    float acc3[5][5];
    if (act) {
        #pragma unroll
        for (int a=0;a<5;a++)
            #pragma unroll
            for (int b2=0;b2<5;b2++) acc3[a][b2]=0.f;
        const float* Ab  = &A[slot*ATS];
        const float* A2b = &A2[slot*ATS];
        #pragma unroll
        for (int w = 0; w < ROWP; w += 4) {
            float4 ar[5], au[5];
            #pragma unroll
            for (int a=0;a<5;a++) ar[a] = *(const float4*)&A2b[(vt+a)*ROWP + w];
            #pragma unroll
            for (int b2=0;b2<5;b2++) au[b2] = *(const float4*)&Ab[(ut+b2)*ROWP + w];
            #pragma unroll
            for (int a=0;a<5;a++)
                #pragma unroll
                for (int b2=0;b2<5;b2++)
                    acc3[a][b2] += ar[a].x*au[b2].x + ar[a].y*au[b2].y
                                 + ar[a].z*au[b2].z + ar[a].w*au[b2].w;
        }
    }

    float* pb = partial + ((size_t)n*NCH + chunk) * SEL;
    for (int e = tid; e < V_*V_; e += 128) {
        const int v = e/V_, u = e%V_;
        float s1=0.f, s2=0.f;
        #pragma unroll
        for (int sl = 0; sl < TTP; ++sl) {
            s1 += A [sl*ATS + v*ROWP + u];
            s2 += A2[sl*ATS + v*ROWP + u];
        }
        pb[e]         = s1;
        pb[V_*V_ + e] = s2;
    }
    __syncthreads();

    if (act) {
        float* Ar = &A[slot*ATS];
        #pragma unroll
        for (int a=0;a<5;a++)
            #pragma unroll
            for (int b2=0;b2<5;b2++) {
                Ar[(vt+a)*ROWP + ut+b2] = acc3[a][b2];
                Ar[(ut+b2)*ROWP + vt+a] = acc3[a][b2];
            }
    }
    __syncthreads();

    for (int e = tid; e < V_*V_; e += 128) {
        const int v = e/V_, u = e%V_;
        float s3=0.f;
        #pragma unroll
        for (int sl = 0; sl < TTP; ++sl) s3 += A[sl*ATS + v*ROWP + u];
        pb[2*V_*V_ + e] = s3;
    }
}

// ---------------------------------------------------------------------------
// K1b: round-5 version, byte-identical.
// ---------------------------------------------------------------------------
__global__ __launch_bounds__(256) void k_reduce(const float* __restrict__ partial,
                                                float* __restrict__ Ssum) {
    const int g = blockIdx.x*256 + threadIdx.x;
    if (g >= N_*SEL) return;
    const int n = g / SEL, j = g % SEL;
    const float* p = partial + (size_t)n*NCH*SEL + j;
    float s = 0.f;
    #pragma unroll 4
    for (int c = 0; c < NCH; ++c) s += p[(size_t)c*SEL];
    Ssum[g] = s;
}

// ---------------------------------------------------------------------------
// K2: round-5 version (best total 83.2us), byte-identical: TT2=10, 256 thr,
// LDS-staged W/scl/off, per-s agg loops, scalar stores. Launched 4x this
// round (idempotent) purely to measure its duration via the total delta.
// ---------------------------------------------------------------------------
__global__ __launch_bounds__(256) void k_out(const float* __restrict__ x,
                                             const float* __restrict__ Ssum,
                                             const float* __restrict__ W,
                                             const float* __restrict__ b,
                                             const float* __restrict__ gamma,
                                             const float* __restrict__ beta,
                                             float* __restrict__ out) {
    const int n = blockIdx.x, tile = blockIdx.y;  // 30 tiles x 10 t
    const int tid = threadIdx.x;

    __shared__ __align__(16) float S_l[3*V_*ROWP];    // 2100
    __shared__ __align__(16) float xsh[TT2*C_*ROWP];  // 840
    __shared__ __align__(16) float Wl[OUT_*12];       // 1152
    __shared__ float scl[OUT_], off[OUT_];

    const float* xn = x + (size_t)n * C_*T_*V_;
    const int t0 = tile * TT2;
    const float inv_bn = rsqrtf(1.0f + 1e-5f);

    for (int i = tid; i < 3*V_*ROWP; i += 256) {
        const int s = i/(V_*ROWP), r = i%(V_*ROWP), v = r/ROWP, u = r%ROWP;
        S_l[i] = (u < V_) ? Ssum[(size_t)n*SEL + s*V_*V_ + v*V_ + u] : 0.f;
    }
    for (int i = tid; i < TT2*C_*ROWP; i += 256) {
        const int tt = i/(C_*ROWP), r = i%(C_*ROWP), c = r/ROWP, u = r%ROWP;
        xsh[i] = (u < V_) ? xn[c*(T_*V_) + (t0+tt)*V_ + u] : 0.f;
    }
    for (int i = tid; i < OUT_*12; i += 256) Wl[i] = W[i];
    if (tid < OUT_) {
        const float sc = gamma[tid] * inv_bn;
        scl[tid] = sc;
        off[tid] = b[tid]*sc + beta[tid];
    }
    __syncthreads();

    if (tid < TT2*V_) {
        const int tt = tid / V_, iv = tid % V_;
        const float* xb = &xsh[tt*C_*ROWP];
        float agg[12];
        agg[0] = (float)T_ * xb[0*ROWP + iv];
        agg[1] = (float)T_ * xb[1*ROWP + iv];
        agg[2] = (float)T_ * xb[2*ROWP + iv];
        #pragma unroll
        for (int s = 1; s < 4; ++s) {
            float a0=0.f, a1=0.f, a2=0.f;
            const float* Srow = &S_l[(s-1)*V_*ROWP + iv*ROWP];
            #pragma unroll
            for (int u4 = 0; u4 < ROWP; u4 += 4) {
                const float4 sv = *(const float4*)&Srow[u4];
                const float4 q0 = *(const float4*)&xb[0*ROWP + u4];
                const float4 q1 = *(const float4*)&xb[1*ROWP + u4];
                const float4 q2 = *(const float4*)&xb[2*ROWP + u4];
                a0 += sv.x*q0.x + sv.y*q0.y + sv.z*q0.z + sv.w*q0.w;
                a1 += sv.x*q1.x + sv.y*q1.y + sv.z*q1.z + sv.w*q1.w;
                a2 += sv.x*q2.x + sv.y*q2.y + sv.z*q2.z + sv.w*q2.w;
            }
            agg[3*s+0]=a0; agg[3*s+1]=a1; agg[3*s+2]=a2;
        }

        float* on = out + (size_t)n*(size_t)OUT_*T_*V_ + t0*V_ + tid;
        #pragma unroll 4
        for (int o = 0; o < OUT_; ++o) {
            const float4 w0 = *(const float4*)&Wl[o*12];
            const float4 w1 = *(const float4*)&Wl[o*12+4];
            const float4 w2 = *(const float4*)&Wl[o*12+8];
            float acc = w0.x*agg[0] + w0.y*agg[1] + w0.z*agg[2] + w0.w*agg[3]
                      + w1.x*agg[4] + w1.y*agg[5] + w1.z*agg[6] + w1.w*agg[7]
                      + w2.x*agg[8] + w2.y*agg[9] + w2.z*agg[10]+ w2.w*agg[11];
            const float rl = fmaxf(acc*scl[o] + off[o], 0.f);
            on[(size_t)o*(T_*V_)] = rl;
        }
    }
}

extern "C" void kernel_launch(void* const* d_in, const int* in_sizes, int n_in,
                              void* d_out, int out_size, void* d_ws, size_t ws_size,
                              hipStream_t stream) {
    const float* x     = (const float*)d_in[0];
    const float* xx    = (const float*)d_in[1];
    const float* W     = (const float*)d_in[2];
    const float* b     = (const float*)d_in[3];
    const float* gamma = (const float*)d_in[4];
    const float* beta  = (const float*)d_in[5];
    float* out  = (float*)d_out;

    float* Ssum    = (float*)d_ws;                  // 240 KB
    float* partial = (float*)d_ws + (size_t)N_*SEL; // 14.4 MB

    k_powsum<<<dim3(N_, NCH), 128, 0, stream>>>(xx, partial);
    k_reduce<<<(N_*SEL + 255)/256, 256, 0, stream>>>(partial, Ssum);
    // MEASUREMENT ROUND: k_out launched 4x (idempotent, identical writes).
    // dur_us - 83.2 ≈ 3 * t(k_out). Intentional, expected regression.
    k_out   <<<dim3(N_, T_/TT2), 256, 0, stream>>>(x, Ssum, W, b, gamma, beta, out);
    k_out   <<<dim3(N_, T_/TT2), 256, 0, stream>>>(x, Ssum, W, b, gamma, beta, out);
    k_out   <<<dim3(N_, T_/TT2), 256, 0, stream>>>(x, Ssum, W, b, gamma, beta, out);
    k_out   <<<dim3(N_, T_/TT2), 256, 0, stream>>>(x, Ssum, W, b, gamma, beta, out);
}

// Round 10
// 60.384 us; speedup vs baseline: 2.8547x; 2.8547x over previous
//
#include <hip/hip_runtime.h>

#define N_   32
#define C_   3
#define T_   300
#define V_   25
#define OUT_ 96
#define ROWP 28              // k_out padded row
#define NCH  60              // partial records per n (15 chunks x 4 waves)
#define TT2  10              // t's per k_out block
#define SEL  (3*V_*V_)       // 1875 floats per sum record

using half8  = __attribute__((ext_vector_type(8))) _Float16;
using floatx4 = __attribute__((ext_vector_type(4))) float;

// ---------------------------------------------------------------------------
// K1 (MFMA rewrite): one WAVE per t (4 waves/block, 5 t's per wave).
// A (25x25, symmetric) is built directly into 16x16x32-f16 fragments:
//   frag F_I: slot (lane,j) holds A[16I+(lane&15)][kb+j], kb=(lane>>4)*8,
//   masked to 0 outside 25x25. Symmetry makes F_I serve as BOTH A- and
//   B-operand (B col = lane&15). Math is invariant to the HW k-slot
//   permutation (both operands share it; contraction sums all k).
// Per t: 4 MFMA (A^2, K=32) + 4 MFMA (A^3 via LDS round-trip of A^2 in the
// verified C/D layout) + 4 MFMA (identity x A accumulates A itself).
// Accumulate 3x4 f32x4 in regs across 5 t's; write compact [3][25][25].
// ---------------------------------------------------------------------------
__global__ __launch_bounds__(256) void k_powsum(const float* __restrict__ xx,
                                                float* __restrict__ partial) {
    const int n = blockIdx.x, chunk = blockIdx.y;   // 15 chunks x 20 t
    const int tid  = threadIdx.x;
    const int wid  = tid >> 6;
    const int lane = tid & 63;
    const int r0   = lane & 15;          // A row / B col within tile
    const int kb   = (lane >> 4) * 8;    // k-slot base (convention; see note)

    __shared__ __align__(16) float xst[4][3][32];    // per-wave x stage
    __shared__ __align__(16) float a2b[4][32][36];   // per-wave A^2 buffer

    // identity fragments (constant): Iblock_I[16I+r][k] = (k == 16I+r)
    half8 I0 = {}, I1 = {};
    #pragma unroll
    for (int j = 0; j < 8; ++j) {
        if (kb + j == r0)      I0[j] = (_Float16)1.0f;
        if (kb + j == 16 + r0) I1[j] = (_Float16)1.0f;
    }

    floatx4 acc[3][4];
    #pragma unroll
    for (int s = 0; s < 3; ++s)
        #pragma unroll
        for (int q = 0; q < 4; ++q)
            #pragma unroll
            for (int r = 0; r < 4; ++r) acc[s][q][r] = 0.f;

    const float* xxn = xx + (size_t)n * C_*T_*V_;
    const bool rowOK1 = (r0 < 9);        // 16+r0 < 25

    for (int tt = 0; tt < 5; ++tt) {
        const int t = chunk*20 + wid*5 + tt;
        // stage 75 floats of x[:, t, :] into this wave's LDS row
        {
            const int i0 = lane;
            if (i0 < 75) xst[wid][i0/25][i0%25] = xxn[(i0/25)*(T_*V_) + t*V_ + (i0%25)];
            const int i1 = 64 + lane;
            if (lane < 11) xst[wid][i1/25][i1%25] = xxn[(i1/25)*(T_*V_) + t*V_ + (i1%25)];
        }
        __syncthreads();

        // build F0 (rows 0-15) and F1 (rows 16-31), masked to 25x25
        float xr0c[3], xr1c[3], xk[3][8];
        #pragma unroll
        for (int c = 0; c < 3; ++c) {
            xr0c[c] = xst[wid][c][r0];
            xr1c[c] = xst[wid][c][16 + r0];
            const float4 k0 = *(const float4*)&xst[wid][c][kb];
            const float4 k1 = *(const float4*)&xst[wid][c][kb + 4];
            xk[c][0]=k0.x; xk[c][1]=k0.y; xk[c][2]=k0.z; xk[c][3]=k0.w;
            xk[c][4]=k1.x; xk[c][5]=k1.y; xk[c][6]=k1.z; xk[c][7]=k1.w;
        }
        half8 F0, F1;
        #pragma unroll
        for (int j = 0; j < 8; ++j) {
            const int  kk  = kb + j;
            const bool kOK = (kk < 25);
            float d0 = xr0c[0]-xk[0][j], d1 = xr0c[1]-xk[1][j], d2 = xr0c[2]-xk[2][j];
            const float a0 = __expf(-(d0*d0 + d1*d1 + d2*d2));
            F0[j] = kOK ? (_Float16)a0 : (_Float16)0.f;
            float e0 = xr1c[0]-xk[0][j], e1 = xr1c[1]-xk[1][j], e2 = xr1c[2]-xk[2][j];
            const float a1 = __expf(-(e0*e0 + e1*e1 + e2*e2));
            F1[j] = (kOK && rowOK1) ? (_Float16)a1 : (_Float16)0.f;
        }

        const floatx4 z = {0.f, 0.f, 0.f, 0.f};
        // A^2 tiles (need per-t values for A^3, so C=0 then add)
        floatx4 d2q[4];
        d2q[0] = __builtin_amdgcn_mfma_f32_16x16x32_f16(F0, F0, z, 0, 0, 0);
        d2q[1] = __builtin_amdgcn_mfma_f32_16x16x32_f16(F0, F1, z, 0, 0, 0);
        d2q[2] = __builtin_amdgcn_mfma_f32_16x16x32_f16(F1, F0, z, 0, 0, 0);
        d2q[3] = __builtin_amdgcn_mfma_f32_16x16x32_f16(F1, F1, z, 0, 0, 0);
        // S1 += A via identity-operand MFMAs (exact: 1.0 in f16)
        acc[0][0] = __builtin_amdgcn_mfma_f32_16x16x32_f16(I0, F0, acc[0][0], 0, 0, 0);
        acc[0][1] = __builtin_amdgcn_mfma_f32_16x16x32_f16(I0, F1, acc[0][1], 0, 0, 0);
        acc[0][2] = __builtin_amdgcn_mfma_f32_16x16x32_f16(I1, F0, acc[0][2], 0, 0, 0);
        acc[0][3] = __builtin_amdgcn_mfma_f32_16x16x32_f16(I1, F1, acc[0][3], 0, 0, 0);
        // S2 += A^2 ; stash A^2 in LDS using the verified C/D layout
        const int rbase = (lane >> 4) * 4;
        #pragma unroll
        for (int q = 0; q < 4; ++q) {
            #pragma unroll
            for (int r = 0; r < 4; ++r) acc[1][q][r] += d2q[q][r];
            const int RB = 16*(q>>1) + rbase, CC = 16*(q&1) + r0;
            #pragma unroll
            for (int r = 0; r < 4; ++r) a2b[wid][RB + r][CC] = d2q[q][r];
        }
        __syncthreads();

        // reload A^2 as fragments (pads are already exact zeros)
        const float4 m0 = *(const float4*)&a2b[wid][r0][kb];
        const float4 m1 = *(const float4*)&a2b[wid][r0][kb + 4];
        const float4 m2 = *(const float4*)&a2b[wid][16 + r0][kb];
        const float4 m3 = *(const float4*)&a2b[wid][16 + r0][kb + 4];
        half8 FA0, FA1;
        FA0[0]=(_Float16)m0.x; FA0[1]=(_Float16)m0.y; FA0[2]=(_Float16)m0.z; FA0[3]=(_Float16)m0.w;
        FA0[4]=(_Float16)m1.x; FA0[5]=(_Float16)m1.y; FA0[6]=(_Float16)m1.z; FA0[7]=(_Float16)m1.w;
        FA1[0]=(_Float16)m2.x; FA1[1]=(_Float16)m2.y; FA1[2]=(_Float16)m2.z; FA1[3]=(_Float16)m2.w;
        FA1[4]=(_Float16)m3.x; FA1[5]=(_Float16)m3.y; FA1[6]=(_Float16)m3.z; FA1[7]=(_Float16)m3.w;
        // S3 += A^2 * A
        acc[2][0] = __builtin_amdgcn_mfma_f32_16x16x32_f16(FA0, F0, acc[2][0], 0, 0, 0);
        acc[2][1] = __builtin_amdgcn_mfma_f32_16x16x32_f16(FA0, F1, acc[2][1], 0, 0, 0);
        acc[2][2] = __builtin_amdgcn_mfma_f32_16x16x32_f16(FA1, F0, acc[2][2], 0, 0, 0);
        acc[2][3] = __builtin_amdgcn_mfma_f32_16x16x32_f16(FA1, F1, acc[2][3], 0, 0, 0);
        __syncthreads();   // before next tt overwrites xst/a2b
    }

    // write this wave's record, compact [3][25][25] (C/D layout -> (R,C))
    float* pb = partial + ((size_t)n*NCH + chunk*4 + wid) * SEL;
    const int rbase = (lane >> 4) * 4;
    #pragma unroll
    for (int s = 0; s < 3; ++s)
        #pragma unroll
        for (int q = 0; q < 4; ++q) {
            const int RB = 16*(q>>1) + rbase, CC = 16*(q&1) + r0;
            if (CC < 25) {
                #pragma unroll
                for (int r = 0; r < 4; ++r) {
                    const int R = RB + r;
                    if (R < 25) pb[s*625 + R*25 + CC] = acc[s][q][r];
                }
            }
        }
}

// ---------------------------------------------------------------------------
// K1b: byte-identical to round 5.
// ---------------------------------------------------------------------------
__global__ __launch_bounds__(256) void k_reduce(const float* __restrict__ partial,
                                                float* __restrict__ Ssum) {
    const int g = blockIdx.x*256 + threadIdx.x;
    if (g >= N_*SEL) return;
    const int n = g / SEL, j = g % SEL;
    const float* p = partial + (size_t)n*NCH*SEL + j;
    float s = 0.f;
    #pragma unroll 4
    for (int c = 0; c < NCH; ++c) s += p[(size_t)c*SEL];
    Ssum[g] = s;
}

// ---------------------------------------------------------------------------
// K2: byte-identical to round 5 (measured 29.7us).
// ---------------------------------------------------------------------------
__global__ __launch_bounds__(256) void k_out(const float* __restrict__ x,
                                             const float* __restrict__ Ssum,
                                             const float* __restrict__ W,
                                             const float* __restrict__ b,
                                             const float* __restrict__ gamma,
                                             const float* __restrict__ beta,
                                             float* __restrict__ out) {
    const int n = blockIdx.x, tile = blockIdx.y;  // 30 tiles x 10 t
    const int tid = threadIdx.x;

    __shared__ __align__(16) float S_l[3*V_*ROWP];    // 2100
    __shared__ __align__(16) float xsh[TT2*C_*ROWP];  // 840
    __shared__ __align__(16) float Wl[OUT_*12];       // 1152
    __shared__ float scl[OUT_], off[OUT_];

    const float* xn = x + (size_t)n * C_*T_*V_;
    const int t0 = tile * TT2;
    const float inv_bn = rsqrtf(1.0f + 1e-5f);

    for (int i = tid; i < 3*V_*ROWP; i += 256) {
        const int s = i/(V_*ROWP), r = i%(V_*ROWP), v = r/ROWP, u = r%ROWP;
        S_l[i] = (u < V_) ? Ssum[(size_t)n*SEL + s*V_*V_ + v*V_ + u] : 0.f;
    }
    for (int i = tid; i < TT2*C_*ROWP; i += 256) {
        const int tt = i/(C_*ROWP), r = i%(C_*ROWP), c = r/ROWP, u = r%ROWP;
        xsh[i] = (u < V_) ? xn[c*(T_*V_) + (t0+tt)*V_ + u] : 0.f;
    }
    for (int i = tid; i < OUT_*12; i += 256) Wl[i] = W[i];
    if (tid < OUT_) {
        const float sc = gamma[tid] * inv_bn;
        scl[tid] = sc;
        off[tid] = b[tid]*sc + beta[tid];
    }
    __syncthreads();

    if (tid < TT2*V_) {
        const int tt = tid / V_, iv = tid % V_;
        const float* xb = &xsh[tt*C_*ROWP];
        float agg[12];
        agg[0] = (float)T_ * xb[0*ROWP + iv];
        agg[1] = (float)T_ * xb[1*ROWP + iv];
        agg[2] = (float)T_ * xb[2*ROWP + iv];
        #pragma unroll
        for (int s = 1; s < 4; ++s) {
            float a0=0.f, a1=0.f, a2=0.f;
            const float* Srow = &S_l[(s-1)*V_*ROWP + iv*ROWP];
            #pragma unroll
            for (int u4 = 0; u4 < ROWP; u4 += 4) {
                const float4 sv = *(const float4*)&Srow[u4];
                const float4 q0 = *(const float4*)&xb[0*ROWP + u4];
                const float4 q1 = *(const float4*)&xb[1*ROWP + u4];
                const float4 q2 = *(const float4*)&xb[2*ROWP + u4];
                a0 += sv.x*q0.x + sv.y*q0.y + sv.z*q0.z + sv.w*q0.w;
                a1 += sv.x*q1.x + sv.y*q1.y + sv.z*q1.z + sv.w*q1.w;
                a2 += sv.x*q2.x + sv.y*q2.y + sv.z*q2.z + sv.w*q2.w;
            }
            agg[3*s+0]=a0; agg[3*s+1]=a1; agg[3*s+2]=a2;
        }

        float* on = out + (size_t)n*(size_t)OUT_*T_*V_ + t0*V_ + tid;
        #pragma unroll 4
        for (int o = 0; o < OUT_; ++o) {
            const float4 w0 = *(const float4*)&Wl[o*12];
            const float4 w1 = *(const float4*)&Wl[o*12+4];
            const float4 w2 = *(const float4*)&Wl[o*12+8];
            float acc = w0.x*agg[0] + w0.y*agg[1] + w0.z*agg[2] + w0.w*agg[3]
                      + w1.x*agg[4] + w1.y*agg[5] + w1.z*agg[6] + w1.w*agg[7]
                      + w2.x*agg[8] + w2.y*agg[9] + w2.z*agg[10]+ w2.w*agg[11];
            const float rl = fmaxf(acc*scl[o] + off[o], 0.f);
            on[(size_t)o*(T_*V_)] = rl;
        }
    }
}

extern "C" void kernel_launch(void* const* d_in, const int* in_sizes, int n_in,
                              void* d_out, int out_size, void* d_ws, size_t ws_size,
                              hipStream_t stream) {
    const float* x     = (const float*)d_in[0];
    const float* xx    = (const float*)d_in[1];
    const float* W     = (const float*)d_in[2];
    const float* b     = (const float*)d_in[3];
    const float* gamma = (const float*)d_in[4];
    const float* beta  = (const float*)d_in[5];
    float* out  = (float*)d_out;

    float* Ssum    = (float*)d_ws;                  // 240 KB
    float* partial = (float*)d_ws + (size_t)N_*SEL; // 14.4 MB (60 recs/n)

    k_powsum<<<dim3(N_, 15), 256, 0, stream>>>(xx, partial);
    k_reduce<<<(N_*SEL + 255)/256, 256, 0, stream>>>(partial, Ssum);
    k_out   <<<dim3(N_, T_/TT2), 256, 0, stream>>>(x, Ssum, W, b, gamma, beta, out);
}

// Round 11
// 59.979 us; speedup vs baseline: 2.8740x; 1.0067x over previous
//
#include <hip/hip_runtime.h>

#define N_   32
#define C_   3
#define T_   300
#define V_   25
#define OUT_ 96
#define ROWP 28              // k_out padded row
#define NCH  60              // partial records per n (15 chunks x 4 waves)
#define TT2  10              // t's per k_out block
#define SEL  (3*V_*V_)       // 1875 floats per sum record

using half8  = __attribute__((ext_vector_type(8))) _Float16;
using floatx4 = __attribute__((ext_vector_type(4))) float;

// ---------------------------------------------------------------------------
// K1 (MFMA): one WAVE per t (4 waves/block, 5 t's per wave). Same math as
// round 10. NEW: epilogue routes accumulators through per-wave LDS and
// stores records with coalesced unit-stride wave-stores (was: 48 scattered
// 4B wave-stores spanning 7.5KB each -> ~64 cache lines per instruction).
// ---------------------------------------------------------------------------
__global__ __launch_bounds__(256) void k_powsum(const float* __restrict__ xx,
                                                float* __restrict__ partial) {
    const int n = blockIdx.x, chunk = blockIdx.y;   // 15 chunks x 20 t
    const int tid  = threadIdx.x;
    const int wid  = tid >> 6;
    const int lane = tid & 63;
    const int r0   = lane & 15;          // A row / B col within tile
    const int kb   = (lane >> 4) * 8;    // k-slot base

    __shared__ __align__(16) float xst[4][3][32];    // per-wave x stage
    __shared__ __align__(16) float a2b[4][32][36];   // per-wave A^2 / epilogue buffer

    // identity fragments: Iblock_I[16I+r][k] = (k == 16I+r)
    half8 I0 = {}, I1 = {};
    #pragma unroll
    for (int j = 0; j < 8; ++j) {
        if (kb + j == r0)      I0[j] = (_Float16)1.0f;
        if (kb + j == 16 + r0) I1[j] = (_Float16)1.0f;
    }

    floatx4 acc[3][4];
    #pragma unroll
    for (int s = 0; s < 3; ++s)
        #pragma unroll
        for (int q = 0; q < 4; ++q)
            #pragma unroll
            for (int r = 0; r < 4; ++r) acc[s][q][r] = 0.f;

    const float* xxn = xx + (size_t)n * C_*T_*V_;
    const bool rowOK1 = (r0 < 9);        // 16+r0 < 25

    for (int tt = 0; tt < 5; ++tt) {
        const int t = chunk*20 + wid*5 + tt;
        {
            const int i0 = lane;
            if (i0 < 75) xst[wid][i0/25][i0%25] = xxn[(i0/25)*(T_*V_) + t*V_ + (i0%25)];
            const int i1 = 64 + lane;
            if (lane < 11) xst[wid][i1/25][i1%25] = xxn[(i1/25)*(T_*V_) + t*V_ + (i1%25)];
        }
        __syncthreads();

        // build F0 (rows 0-15) and F1 (rows 16-31), masked to 25x25
        float xr0c[3], xr1c[3], xk[3][8];
        #pragma unroll
        for (int c = 0; c < 3; ++c) {
            xr0c[c] = xst[wid][c][r0];
            xr1c[c] = xst[wid][c][16 + r0];
            const float4 k0 = *(const float4*)&xst[wid][c][kb];
            const float4 k1 = *(const float4*)&xst[wid][c][kb + 4];
            xk[c][0]=k0.x; xk[c][1]=k0.y; xk[c][2]=k0.z; xk[c][3]=k0.w;
            xk[c][4]=k1.x; xk[c][5]=k1.y; xk[c][6]=k1.z; xk[c][7]=k1.w;
        }
        half8 F0, F1;
        #pragma unroll
        for (int j = 0; j < 8; ++j) {
            const int  kk  = kb + j;
            const bool kOK = (kk < 25);
            float d0 = xr0c[0]-xk[0][j], d1 = xr0c[1]-xk[1][j], d2 = xr0c[2]-xk[2][j];
            const float a0 = __expf(-(d0*d0 + d1*d1 + d2*d2));
            F0[j] = kOK ? (_Float16)a0 : (_Float16)0.f;
            float e0 = xr1c[0]-xk[0][j], e1 = xr1c[1]-xk[1][j], e2 = xr1c[2]-xk[2][j];
            const float a1 = __expf(-(e0*e0 + e1*e1 + e2*e2));
            F1[j] = (kOK && rowOK1) ? (_Float16)a1 : (_Float16)0.f;
        }

        const floatx4 z = {0.f, 0.f, 0.f, 0.f};
        floatx4 d2q[4];
        d2q[0] = __builtin_amdgcn_mfma_f32_16x16x32_f16(F0, F0, z, 0, 0, 0);
        d2q[1] = __builtin_amdgcn_mfma_f32_16x16x32_f16(F0, F1, z, 0, 0, 0);
        d2q[2] = __builtin_amdgcn_mfma_f32_16x16x32_f16(F1, F0, z, 0, 0, 0);
        d2q[3] = __builtin_amdgcn_mfma_f32_16x16x32_f16(F1, F1, z, 0, 0, 0);
        acc[0][0] = __builtin_amdgcn_mfma_f32_16x16x32_f16(I0, F0, acc[0][0], 0, 0, 0);
        acc[0][1] = __builtin_amdgcn_mfma_f32_16x16x32_f16(I0, F1, acc[0][1], 0, 0, 0);
        acc[0][2] = __builtin_amdgcn_mfma_f32_16x16x32_f16(I1, F0, acc[0][2], 0, 0, 0);
        acc[0][3] = __builtin_amdgcn_mfma_f32_16x16x32_f16(I1, F1, acc[0][3], 0, 0, 0);
        const int rbase = (lane >> 4) * 4;
        #pragma unroll
        for (int q = 0; q < 4; ++q) {
            #pragma unroll
            for (int r = 0; r < 4; ++r) acc[1][q][r] += d2q[q][r];
            const int RB = 16*(q>>1) + rbase, CC = 16*(q&1) + r0;
            #pragma unroll
            for (int r = 0; r < 4; ++r) a2b[wid][RB + r][CC] = d2q[q][r];
        }
        __syncthreads();

        const float4 m0 = *(const float4*)&a2b[wid][r0][kb];
        const float4 m1 = *(const float4*)&a2b[wid][r0][kb + 4];
        const float4 m2 = *(const float4*)&a2b[wid][16 + r0][kb];
        const float4 m3 = *(const float4*)&a2b[wid][16 + r0][kb + 4];
        half8 FA0, FA1;
        FA0[0]=(_Float16)m0.x; FA0[1]=(_Float16)m0.y; FA0[2]=(_Float16)m0.z; FA0[3]=(_Float16)m0.w;
        FA0[4]=(_Float16)m1.x; FA0[5]=(_Float16)m1.y; FA0[6]=(_Float16)m1.z; FA0[7]=(_Float16)m1.w;
        FA1[0]=(_Float16)m2.x; FA1[1]=(_Float16)m2.y; FA1[2]=(_Float16)m2.z; FA1[3]=(_Float16)m2.w;
        FA1[4]=(_Float16)m3.x; FA1[5]=(_Float16)m3.y; FA1[6]=(_Float16)m3.z; FA1[7]=(_Float16)m3.w;
        acc[2][0] = __builtin_amdgcn_mfma_f32_16x16x32_f16(FA0, F0, acc[2][0], 0, 0, 0);
        acc[2][1] = __builtin_amdgcn_mfma_f32_16x16x32_f16(FA0, F1, acc[2][1], 0, 0, 0);
        acc[2][2] = __builtin_amdgcn_mfma_f32_16x16x32_f16(FA1, F0, acc[2][2], 0, 0, 0);
        acc[2][3] = __builtin_amdgcn_mfma_f32_16x16x32_f16(FA1, F1, acc[2][3], 0, 0, 0);
        __syncthreads();   // before next tt overwrites xst/a2b
    }

    // ---- epilogue v2: accs -> per-wave LDS (C/D-layout scatter, cheap) ->
    //      linear read-back -> COALESCED unit-stride record stores.
    float* pb = partial + ((size_t)n*NCH + chunk*4 + wid) * SEL;
    const int rbase = (lane >> 4) * 4;
    #pragma unroll
    for (int s = 0; s < 3; ++s) {
        #pragma unroll
        for (int q = 0; q < 4; ++q) {
            const int RB = 16*(q>>1) + rbase, CC = 16*(q&1) + r0;
            #pragma unroll
            for (int r = 0; r < 4; ++r) a2b[wid][RB + r][CC] = acc[s][q][r];
        }
        __syncthreads();   // make this wave's writes visible to all its lanes
        for (int i = lane; i < V_*V_; i += 64)
            pb[s*V_*V_ + i] = a2b[wid][i/V_][i%V_];
        __syncthreads();   // before next s overwrites a2b
    }
}

// ---------------------------------------------------------------------------
// K1b: full unroll -> 60 loads in flight (was unroll 4: latency-serialized
// at 0.92 waves/SIMD).
// ---------------------------------------------------------------------------
__global__ __launch_bounds__(256) void k_reduce(const float* __restrict__ partial,
                                                float* __restrict__ Ssum) {
    const int g = blockIdx.x*256 + threadIdx.x;
    if (g >= N_*SEL) return;
    const int n = g / SEL, j = g % SEL;
    const float* p = partial + (size_t)n*NCH*SEL + j;
    float s = 0.f;
    #pragma unroll
    for (int c = 0; c < NCH; ++c) s += p[(size_t)c*SEL];
    Ssum[g] = s;
}

// ---------------------------------------------------------------------------
// K2: byte-identical to round 5 (measured 29.7us in round 9).
// ---------------------------------------------------------------------------
__global__ __launch_bounds__(256) void k_out(const float* __restrict__ x,
                                             const float* __restrict__ Ssum,
                                             const float* __restrict__ W,
                                             const float* __restrict__ b,
                                             const float* __restrict__ gamma,
                                             const float* __restrict__ beta,
                                             float* __restrict__ out) {
    const int n = blockIdx.x, tile = blockIdx.y;  // 30 tiles x 10 t
    const int tid = threadIdx.x;

    __shared__ __align__(16) float S_l[3*V_*ROWP];    // 2100
    __shared__ __align__(16) float xsh[TT2*C_*ROWP];  // 840
    __shared__ __align__(16) float Wl[OUT_*12];       // 1152
    __shared__ float scl[OUT_], off[OUT_];

    const float* xn = x + (size_t)n * C_*T_*V_;
    const int t0 = tile * TT2;
    const float inv_bn = rsqrtf(1.0f + 1e-5f);

    for (int i = tid; i < 3*V_*ROWP; i += 256) {
        const int s = i/(V_*ROWP), r = i%(V_*ROWP), v = r/ROWP, u = r%ROWP;
        S_l[i] = (u < V_) ? Ssum[(size_t)n*SEL + s*V_*V_ + v*V_ + u] : 0.f;
    }
    for (int i = tid; i < TT2*C_*ROWP; i += 256) {
        const int tt = i/(C_*ROWP), r = i%(C_*ROWP), c = r/ROWP, u = r%ROWP;
        xsh[i] = (u < V_) ? xn[c*(T_*V_) + (t0+tt)*V_ + u] : 0.f;
    }
    for (int i = tid; i < OUT_*12; i += 256) Wl[i] = W[i];
    if (tid < OUT_) {
        const float sc = gamma[tid] * inv_bn;
        scl[tid] = sc;
        off[tid] = b[tid]*sc + beta[tid];
    }
    __syncthreads();

    if (tid < TT2*V_) {
        const int tt = tid / V_, iv = tid % V_;
        const float* xb = &xsh[tt*C_*ROWP];
        float agg[12];
        agg[0] = (float)T_ * xb[0*ROWP + iv];
        agg[1] = (float)T_ * xb[1*ROWP + iv];
        agg[2] = (float)T_ * xb[2*ROWP + iv];
        #pragma unroll
        for (int s = 1; s < 4; ++s) {
            float a0=0.f, a1=0.f, a2=0.f;
            const float* Srow = &S_l[(s-1)*V_*ROWP + iv*ROWP];
            #pragma unroll
            for (int u4 = 0; u4 < ROWP; u4 += 4) {
                const float4 sv = *(const float4*)&Srow[u4];
                const float4 q0 = *(const float4*)&xb[0*ROWP + u4];
                const float4 q1 = *(const float4*)&xb[1*ROWP + u4];
                const float4 q2 = *(const float4*)&xb[2*ROWP + u4];
                a0 += sv.x*q0.x + sv.y*q0.y + sv.z*q0.z + sv.w*q0.w;
                a1 += sv.x*q1.x + sv.y*q1.y + sv.z*q1.z + sv.w*q1.w;
                a2 += sv.x*q2.x + sv.y*q2.y + sv.z*q2.z + sv.w*q2.w;
            }
            agg[3*s+0]=a0; agg[3*s+1]=a1; agg[3*s+2]=a2;
        }

        float* on = out + (size_t)n*(size_t)OUT_*T_*V_ + t0*V_ + tid;
        #pragma unroll 4
        for (int o = 0; o < OUT_; ++o) {
            const float4 w0 = *(const float4*)&Wl[o*12];
            const float4 w1 = *(const float4*)&Wl[o*12+4];
            const float4 w2 = *(const float4*)&Wl[o*12+8];
            float acc = w0.x*agg[0] + w0.y*agg[1] + w0.z*agg[2] + w0.w*agg[3]
                      + w1.x*agg[4] + w1.y*agg[5] + w1.z*agg[6] + w1.w*agg[7]
                      + w2.x*agg[8] + w2.y*agg[9] + w2.z*agg[10]+ w2.w*agg[11];
            const float rl = fmaxf(acc*scl[o] + off[o], 0.f);
            on[(size_t)o*(T_*V_)] = rl;
        }
    }
}

extern "C" void kernel_launch(void* const* d_in, const int* in_sizes, int n_in,
                              void* d_out, int out_size, void* d_ws, size_t ws_size,
                              hipStream_t stream) {
    const float* x     = (const float*)d_in[0];
    const float* xx    = (const float*)d_in[1];
    const float* W     = (const float*)d_in[2];
    const float* b     = (const float*)d_in[3];
    const float* gamma = (const float*)d_in[4];
    const float* beta  = (const float*)d_in[5];
    float* out  = (float*)d_out;

    float* Ssum    = (float*)d_ws;                  // 240 KB
    float* partial = (float*)d_ws + (size_t)N_*SEL; // 14.4 MB (60 recs/n)

    k_powsum<<<dim3(N_, 15), 256, 0, stream>>>(xx, partial);
    k_reduce<<<(N_*SEL + 255)/256, 256, 0, stream>>>(partial, Ssum);
    k_out   <<<dim3(N_, T_/TT2), 256, 0, stream>>>(x, Ssum, W, b, gamma, beta, out);
}